// Round 1
// baseline (7066.782 us; speedup 1.0000x reference)
//
#include <hip/hip_runtime.h>

#define D 64
#define NUM_LAYERS 4

// ---------------- kernels ----------------

__global__ void deg_kernel(const int* __restrict__ dst, float* __restrict__ deg, int E) {
    int e = blockIdx.x * blockDim.x + threadIdx.x;
    if (e < E) atomicAdd(&deg[dst[e]], 1.0f);
}

// deg -> deg_inv_sqrt in place
__global__ void dis_kernel(float* __restrict__ deg, int N) {
    int i = blockIdx.x * blockDim.x + threadIdx.x;
    if (i < N) {
        float d = deg[i];
        deg[i] = (d > 0.0f) ? rsqrtf(d) : 0.0f;
    }
}

__global__ void norm_kernel(const int* __restrict__ src, const int* __restrict__ dst,
                            const float* __restrict__ dis, float* __restrict__ norm, int E) {
    int e = blockIdx.x * blockDim.x + threadIdx.x;
    if (e < E) norm[e] = dis[src[e]] * dis[dst[e]];
}

// concat users/items into A, and into acc (d_out)
__global__ void init_kernel(const float* __restrict__ users, const float* __restrict__ items,
                            float* __restrict__ A, float* __restrict__ acc,
                            int nu_elems, int total_elems) {
    int i = blockIdx.x * blockDim.x + threadIdx.x;
    if (i < total_elems) {
        float v = (i < nu_elems) ? users[i] : items[i - nu_elems];
        A[i] = v;
        acc[i] = v;
    }
}

// one edge handled by 16 threads, each owning a float4 chunk of the 64-wide row
__global__ void scatter_kernel(const int* __restrict__ src, const int* __restrict__ dst,
                               const float* __restrict__ norm,
                               const float* __restrict__ A, float* __restrict__ B, int total) {
    int t = blockIdx.x * blockDim.x + threadIdx.x;
    if (t >= total) return;
    int e  = t >> 4;        // edge index (wave-uniform per 16 lanes)
    int d4 = t & 15;        // which float4 of the row
    int s  = src[e];
    int dd = dst[e];
    float w = norm[e];
    const float4* Arow = (const float4*)(A + (long long)s * D);
    float4 v = Arow[d4];
    float* Brow = B + (long long)dd * D + d4 * 4;
    atomicAdd(Brow + 0, w * v.x);
    atomicAdd(Brow + 1, w * v.y);
    atomicAdd(Brow + 2, w * v.z);
    atomicAdd(Brow + 3, w * v.w);
}

__global__ void accum_kernel(float* __restrict__ acc, const float* __restrict__ B, int total4) {
    int i = blockIdx.x * blockDim.x + threadIdx.x;
    if (i < total4) {
        float4 a = ((const float4*)acc)[i];
        float4 b = ((const float4*)B)[i];
        a.x += b.x; a.y += b.y; a.z += b.z; a.w += b.w;
        ((float4*)acc)[i] = a;
    }
}

__global__ void scale_kernel(float* __restrict__ acc, int total4, float s) {
    int i = blockIdx.x * blockDim.x + threadIdx.x;
    if (i < total4) {
        float4 a = ((const float4*)acc)[i];
        a.x *= s; a.y *= s; a.z *= s; a.w *= s;
        ((float4*)acc)[i] = a;
    }
}

// ---------------- launch ----------------

extern "C" void kernel_launch(void* const* d_in, const int* in_sizes, int n_in,
                              void* d_out, int out_size, void* d_ws, size_t ws_size,
                              hipStream_t stream) {
    const float* users = (const float*)d_in[0];
    const float* items = (const float*)d_in[1];
    const int*   eidx  = (const int*)d_in[2];

    const int nu = in_sizes[0] / D;        // 100000
    const int ni = in_sizes[1] / D;        // 50000
    const int N  = nu + ni;                // 150000
    const int E  = in_sizes[2] / 2;        // 2000000
    const int Nf = N * D;                  // 9.6M floats

    const int* src = eidx;
    const int* dst = eidx + E;

    // workspace layout (256B aligned chunks)
    char* ws = (char*)d_ws;
    size_t off = 0;
    auto alloc = [&](size_t bytes) {
        char* p = ws + off;
        off += (bytes + 255) & ~(size_t)255;
        return p;
    };
    float* deg  = (float*)alloc((size_t)N * 4);       // becomes deg_inv_sqrt in place
    float* norm = (float*)alloc((size_t)E * 4);
    float* bufA = (float*)alloc((size_t)Nf * 4);
    float* bufB = (float*)alloc((size_t)Nf * 4);

    const int B256 = 256;
    auto blocks = [](long long n, int b) { return (int)((n + b - 1) / b); };

    // 1. degree histogram
    hipMemsetAsync(deg, 0, (size_t)N * 4, stream);
    deg_kernel<<<blocks(E, B256), B256, 0, stream>>>(dst, deg, E);
    // 2. deg_inv_sqrt
    dis_kernel<<<blocks(N, B256), B256, 0, stream>>>(deg, N);
    // 3. per-edge norm
    norm_kernel<<<blocks(E, B256), B256, 0, stream>>>(src, dst, deg, norm, E);
    // 4. init emb + acc
    init_kernel<<<blocks(Nf, B256), B256, 0, stream>>>(users, items, bufA, (float*)d_out, nu * D, Nf);

    // 5. propagation layers
    float* A = bufA;
    float* Bp = bufB;
    const int scatter_total = E * (D / 4);   // 32M threads
    for (int l = 0; l < NUM_LAYERS; ++l) {
        hipMemsetAsync(Bp, 0, (size_t)Nf * 4, stream);
        scatter_kernel<<<blocks(scatter_total, B256), B256, 0, stream>>>(src, dst, norm, A, Bp, scatter_total);
        accum_kernel<<<blocks(Nf / 4, B256), B256, 0, stream>>>((float*)d_out, Bp, Nf / 4);
        float* t = A; A = Bp; Bp = t;
    }

    // 6. final scale by 1/(L+1)^2 = 1/25
    scale_kernel<<<blocks(Nf / 4, B256), B256, 0, stream>>>((float*)d_out, Nf / 4, 1.0f / 25.0f);
}

// Round 2
// 760.369 us; speedup vs baseline: 9.2939x; 9.2939x over previous
//
#include <hip/hip_runtime.h>

#define D 64
#define NUM_LAYERS 4

// ---------------- CSR build ----------------

__global__ void cnt_kernel(const int* __restrict__ dst, int* __restrict__ cnt, int E) {
    int e = blockIdx.x * blockDim.x + threadIdx.x;
    if (e < E) atomicAdd(&cnt[dst[e]], 1);
}

__global__ void dis_kernel(const int* __restrict__ cnt, float* __restrict__ dis, int N) {
    int i = blockIdx.x * blockDim.x + threadIdx.x;
    if (i < N) {
        int c = cnt[i];
        dis[i] = (c > 0) ? rsqrtf((float)c) : 0.0f;
    }
}

// block-local exclusive scan; per-block totals to partials
__global__ void scan1_kernel(const int* __restrict__ cnt, int* __restrict__ excl,
                             int* __restrict__ partials, int N) {
    __shared__ int sm[256];
    int i = blockIdx.x * 256 + threadIdx.x;
    int v = (i < N) ? cnt[i] : 0;
    sm[threadIdx.x] = v;
    __syncthreads();
    for (int ofs = 1; ofs < 256; ofs <<= 1) {
        int t = (threadIdx.x >= ofs) ? sm[threadIdx.x - ofs] : 0;
        __syncthreads();
        sm[threadIdx.x] += t;
        __syncthreads();
    }
    if (i < N) excl[i] = sm[threadIdx.x] - v;
    if (threadIdx.x == 255) partials[blockIdx.x] = sm[255];
}

// single-block exclusive scan of partials (nb <= 1024)
__global__ void scan2_kernel(int* __restrict__ partials, int nb) {
    __shared__ int sm[1024];
    int v = (threadIdx.x < nb) ? partials[threadIdx.x] : 0;
    sm[threadIdx.x] = v;
    __syncthreads();
    for (int ofs = 1; ofs < 1024; ofs <<= 1) {
        int t = (threadIdx.x >= ofs) ? sm[threadIdx.x - ofs] : 0;
        __syncthreads();
        sm[threadIdx.x] += t;
        __syncthreads();
    }
    if (threadIdx.x < nb) partials[threadIdx.x] = sm[threadIdx.x] - v;
}

// add block offsets -> row_start (exclusive prefix over all N); also cursor copy
__global__ void scan3_kernel(int* __restrict__ row_start, const int* __restrict__ partials,
                             int* __restrict__ cursor, int N, int E) {
    int i = blockIdx.x * 256 + threadIdx.x;
    if (i < N) {
        int v = row_start[i] + partials[blockIdx.x];
        row_start[i] = v;
        cursor[i] = v;
    }
    if (i == 0) row_start[N] = E;
}

__global__ void place_kernel(const int* __restrict__ src, const int* __restrict__ dst,
                             const float* __restrict__ dis, int* __restrict__ cursor,
                             int* __restrict__ csr_src, float* __restrict__ csr_w, int E) {
    int e = blockIdx.x * blockDim.x + threadIdx.x;
    if (e < E) {
        int s = src[e], d = dst[e];
        int slot = atomicAdd(&cursor[d], 1);
        csr_src[slot] = s;
        csr_w[slot]   = dis[s] * dis[d];
    }
}

// ---------------- propagation ----------------

__global__ void init_kernel(const float* __restrict__ users, const float* __restrict__ items,
                            float* __restrict__ A, float* __restrict__ acc,
                            int nu_elems, int total_elems) {
    int i = blockIdx.x * blockDim.x + threadIdx.x;
    if (i < total_elems) {
        float v = (i < nu_elems) ? users[i] : items[i - nu_elems];
        A[i] = v;
        acc[i] = v;
    }
}

// one wave (64 lanes) per destination node; lane owns one float of the row
__global__ void gather_kernel(const int* __restrict__ row_start,
                              const int* __restrict__ csr_src,
                              const float* __restrict__ csr_w,
                              const float* __restrict__ A,
                              float* __restrict__ B,
                              float* __restrict__ acc,
                              int N, int write_B) {
    int wave = (blockIdx.x * blockDim.x + threadIdx.x) >> 6;
    int lane = threadIdx.x & 63;
    if (wave >= N) return;
    int beg = row_start[wave];
    int end = row_start[wave + 1];
    float sum = 0.0f;
    int j = beg;
    for (; j + 4 <= end; j += 4) {
        int   s0 = csr_src[j],   s1 = csr_src[j+1], s2 = csr_src[j+2], s3 = csr_src[j+3];
        float w0 = csr_w[j],     w1 = csr_w[j+1],   w2 = csr_w[j+2],   w3 = csr_w[j+3];
        float a0 = A[(size_t)s0 * D + lane];
        float a1 = A[(size_t)s1 * D + lane];
        float a2 = A[(size_t)s2 * D + lane];
        float a3 = A[(size_t)s3 * D + lane];
        sum += w0 * a0;
        sum += w1 * a1;
        sum += w2 * a2;
        sum += w3 * a3;
    }
    for (; j < end; ++j)
        sum += csr_w[j] * A[(size_t)csr_src[j] * D + lane];
    size_t o = (size_t)wave * D + lane;
    if (write_B) B[o] = sum;
    acc[o] += sum;
}

__global__ void scale_kernel(float* __restrict__ acc, int total4, float s) {
    int i = blockIdx.x * blockDim.x + threadIdx.x;
    if (i < total4) {
        float4 a = ((const float4*)acc)[i];
        a.x *= s; a.y *= s; a.z *= s; a.w *= s;
        ((float4*)acc)[i] = a;
    }
}

// ---------------- launch ----------------

extern "C" void kernel_launch(void* const* d_in, const int* in_sizes, int n_in,
                              void* d_out, int out_size, void* d_ws, size_t ws_size,
                              hipStream_t stream) {
    const float* users = (const float*)d_in[0];
    const float* items = (const float*)d_in[1];
    const int*   eidx  = (const int*)d_in[2];

    const int nu = in_sizes[0] / D;    // 100000
    const int ni = in_sizes[1] / D;    // 50000
    const int N  = nu + ni;            // 150000
    const int E  = in_sizes[2] / 2;    // 2000000
    const int Nf = N * D;              // 9.6M floats

    const int* src = eidx;
    const int* dst = eidx + E;

    char* ws = (char*)d_ws;
    size_t off = 0;
    auto alloc = [&](size_t bytes) {
        char* p = ws + off;
        off += (bytes + 255) & ~(size_t)255;
        return p;
    };
    int*   cnt       = (int*)alloc((size_t)N * 4);
    float* dis       = (float*)alloc((size_t)N * 4);
    int*   row_start = (int*)alloc((size_t)(N + 1) * 4);
    int*   cursor    = (int*)alloc((size_t)N * 4);
    int*   partials  = (int*)alloc(1024 * 4);
    int*   csr_src   = (int*)alloc((size_t)E * 4);
    float* csr_w     = (float*)alloc((size_t)E * 4);
    float* bufA      = (float*)alloc((size_t)Nf * 4);
    float* bufB      = (float*)alloc((size_t)Nf * 4);

    const int B256 = 256;
    auto blocks = [](long long n, int b) { return (int)((n + b - 1) / b); };
    const int nbN = blocks(N, B256);   // 586

    // 1. degree histogram + deg_inv_sqrt
    hipMemsetAsync(cnt, 0, (size_t)N * 4, stream);
    cnt_kernel<<<blocks(E, B256), B256, 0, stream>>>(dst, cnt, E);
    dis_kernel<<<nbN, B256, 0, stream>>>(cnt, dis, N);

    // 2. exclusive scan of cnt -> row_start, cursor
    scan1_kernel<<<nbN, B256, 0, stream>>>(cnt, row_start, partials, N);
    scan2_kernel<<<1, 1024, 0, stream>>>(partials, nbN);
    scan3_kernel<<<nbN, B256, 0, stream>>>(row_start, partials, cursor, N, E);

    // 3. place edges (counting sort by dst), fusing norm computation
    place_kernel<<<blocks(E, B256), B256, 0, stream>>>(src, dst, dis, cursor, csr_src, csr_w, E);

    // 4. init emb + acc
    init_kernel<<<blocks(Nf, B256), B256, 0, stream>>>(users, items, bufA, (float*)d_out, nu * D, Nf);

    // 5. propagation layers: wave-per-node gather, acc fused
    float* A  = bufA;
    float* Bp = bufB;
    const int waves_per_block = B256 / 64;
    const int ggrid = blocks(N, waves_per_block);
    for (int l = 0; l < NUM_LAYERS; ++l) {
        int write_B = (l < NUM_LAYERS - 1) ? 1 : 0;
        gather_kernel<<<ggrid, B256, 0, stream>>>(row_start, csr_src, csr_w, A, Bp, (float*)d_out, N, write_B);
        float* t = A; A = Bp; Bp = t;
    }

    // 6. final scale by 1/25
    scale_kernel<<<blocks(Nf / 4, B256), B256, 0, stream>>>((float*)d_out, Nf / 4, 1.0f / 25.0f);
}

// Round 3
// 674.893 us; speedup vs baseline: 10.4710x; 1.1267x over previous
//
#include <hip/hip_runtime.h>
#include <hip/hip_bf16.h>

#define D 64
#define NUM_LAYERS 4

// ---------------- CSR build ----------------

__global__ void cnt_kernel(const int* __restrict__ dst, int* __restrict__ cnt, int E) {
    int e = blockIdx.x * blockDim.x + threadIdx.x;
    if (e < E) atomicAdd(&cnt[dst[e]], 1);
}

__global__ void dis_kernel(const int* __restrict__ cnt, float* __restrict__ dis, int N) {
    int i = blockIdx.x * blockDim.x + threadIdx.x;
    if (i < N) {
        int c = cnt[i];
        dis[i] = (c > 0) ? rsqrtf((float)c) : 0.0f;
    }
}

// block-local exclusive scan; per-block totals to partials
__global__ void scan1_kernel(const int* __restrict__ cnt, int* __restrict__ excl,
                             int* __restrict__ partials, int N) {
    __shared__ int sm[256];
    int i = blockIdx.x * 256 + threadIdx.x;
    int v = (i < N) ? cnt[i] : 0;
    sm[threadIdx.x] = v;
    __syncthreads();
    for (int ofs = 1; ofs < 256; ofs <<= 1) {
        int t = (threadIdx.x >= ofs) ? sm[threadIdx.x - ofs] : 0;
        __syncthreads();
        sm[threadIdx.x] += t;
        __syncthreads();
    }
    if (i < N) excl[i] = sm[threadIdx.x] - v;
    if (threadIdx.x == 255) partials[blockIdx.x] = sm[255];
}

// single-block exclusive scan of partials (nb <= 1024)
__global__ void scan2_kernel(int* __restrict__ partials, int nb) {
    __shared__ int sm[1024];
    int v = (threadIdx.x < nb) ? partials[threadIdx.x] : 0;
    sm[threadIdx.x] = v;
    __syncthreads();
    for (int ofs = 1; ofs < 1024; ofs <<= 1) {
        int t = (threadIdx.x >= ofs) ? sm[threadIdx.x - ofs] : 0;
        __syncthreads();
        sm[threadIdx.x] += t;
        __syncthreads();
    }
    if (threadIdx.x < nb) partials[threadIdx.x] = sm[threadIdx.x] - v;
}

__global__ void scan3_kernel(int* __restrict__ row_start, const int* __restrict__ partials,
                             int* __restrict__ cursor, int N, int E) {
    int i = blockIdx.x * 256 + threadIdx.x;
    if (i < N) {
        int v = row_start[i] + partials[blockIdx.x];
        row_start[i] = v;
        cursor[i] = v;
    }
    if (i == 0) row_start[N] = E;
}

// counting-sort edges by dst; pack {src, norm} into one 8B slot
__global__ void place_kernel(const int* __restrict__ src, const int* __restrict__ dst,
                             const float* __restrict__ dis, int* __restrict__ cursor,
                             int2* __restrict__ csr, int E) {
    int e = blockIdx.x * blockDim.x + threadIdx.x;
    if (e < E) {
        int s = src[e], d = dst[e];
        int slot = atomicAdd(&cursor[d], 1);
        int2 v;
        v.x = s;
        v.y = __float_as_int(dis[s] * dis[d]);
        csr[slot] = v;
    }
}

// ---------------- propagation ----------------

__global__ void init_kernel(const float* __restrict__ users, const float* __restrict__ items,
                            __hip_bfloat16* __restrict__ A, float* __restrict__ acc,
                            int nu_elems, int total_elems) {
    int i = blockIdx.x * blockDim.x + threadIdx.x;
    if (i < total_elems) {
        float v = (i < nu_elems) ? users[i] : items[i - nu_elems];
        A[i] = __float2bfloat16(v);
        acc[i] = v;
    }
}

// one wave (64 lanes) per destination node; lane owns one bf16 column
__global__ void gather_kernel(const int* __restrict__ row_start,
                              const int2* __restrict__ csr,
                              const __hip_bfloat16* __restrict__ A,
                              __hip_bfloat16* __restrict__ B,
                              float* __restrict__ acc,
                              int N, int write_B) {
    int wave = (blockIdx.x * blockDim.x + threadIdx.x) >> 6;
    int lane = threadIdx.x & 63;
    if (wave >= N) return;
    int beg = row_start[wave];
    int end = row_start[wave + 1];
    float sum = 0.0f;
    int j = beg;
    for (; j + 4 <= end; j += 4) {
        int2 e0 = csr[j], e1 = csr[j + 1], e2 = csr[j + 2], e3 = csr[j + 3];
        float a0 = __bfloat162float(A[(size_t)e0.x * D + lane]);
        float a1 = __bfloat162float(A[(size_t)e1.x * D + lane]);
        float a2 = __bfloat162float(A[(size_t)e2.x * D + lane]);
        float a3 = __bfloat162float(A[(size_t)e3.x * D + lane]);
        sum += __int_as_float(e0.y) * a0;
        sum += __int_as_float(e1.y) * a1;
        sum += __int_as_float(e2.y) * a2;
        sum += __int_as_float(e3.y) * a3;
    }
    for (; j < end; ++j) {
        int2 e = csr[j];
        sum += __int_as_float(e.y) * __bfloat162float(A[(size_t)e.x * D + lane]);
    }
    size_t o = (size_t)wave * D + lane;
    if (write_B) B[o] = __float2bfloat16(sum);
    acc[o] += sum;
}

__global__ void scale_kernel(float* __restrict__ acc, int total4, float s) {
    int i = blockIdx.x * blockDim.x + threadIdx.x;
    if (i < total4) {
        float4 a = ((const float4*)acc)[i];
        a.x *= s; a.y *= s; a.z *= s; a.w *= s;
        ((float4*)acc)[i] = a;
    }
}

// ---------------- launch ----------------

extern "C" void kernel_launch(void* const* d_in, const int* in_sizes, int n_in,
                              void* d_out, int out_size, void* d_ws, size_t ws_size,
                              hipStream_t stream) {
    const float* users = (const float*)d_in[0];
    const float* items = (const float*)d_in[1];
    const int*   eidx  = (const int*)d_in[2];

    const int nu = in_sizes[0] / D;    // 100000
    const int ni = in_sizes[1] / D;    // 50000
    const int N  = nu + ni;            // 150000
    const int E  = in_sizes[2] / 2;    // 2000000
    const int Nf = N * D;              // 9.6M elems

    const int* src = eidx;
    const int* dst = eidx + E;

    char* ws = (char*)d_ws;
    size_t off = 0;
    auto alloc = [&](size_t bytes) {
        char* p = ws + off;
        off += (bytes + 255) & ~(size_t)255;
        return p;
    };
    int*   cnt       = (int*)alloc((size_t)N * 4);
    float* dis       = (float*)alloc((size_t)N * 4);
    int*   row_start = (int*)alloc((size_t)(N + 1) * 4);
    int*   cursor    = (int*)alloc((size_t)N * 4);
    int*   partials  = (int*)alloc(1024 * 4);
    int2*  csr       = (int2*)alloc((size_t)E * 8);
    __hip_bfloat16* bufA = (__hip_bfloat16*)alloc((size_t)Nf * 2);
    __hip_bfloat16* bufB = (__hip_bfloat16*)alloc((size_t)Nf * 2);

    const int B256 = 256;
    auto blocks = [](long long n, int b) { return (int)((n + b - 1) / b); };
    const int nbN = blocks(N, B256);   // 586

    // 1. degree histogram + deg_inv_sqrt
    hipMemsetAsync(cnt, 0, (size_t)N * 4, stream);
    cnt_kernel<<<blocks(E, B256), B256, 0, stream>>>(dst, cnt, E);
    dis_kernel<<<nbN, B256, 0, stream>>>(cnt, dis, N);

    // 2. exclusive scan of cnt -> row_start, cursor
    scan1_kernel<<<nbN, B256, 0, stream>>>(cnt, row_start, partials, N);
    scan2_kernel<<<1, 1024, 0, stream>>>(partials, nbN);
    scan3_kernel<<<nbN, B256, 0, stream>>>(row_start, partials, cursor, N, E);

    // 3. place edges (counting sort by dst), packed {src, norm}
    place_kernel<<<blocks(E, B256), B256, 0, stream>>>(src, dst, dis, cursor, csr, E);

    // 4. init emb (bf16) + acc (f32)
    init_kernel<<<blocks(Nf, B256), B256, 0, stream>>>(users, items, bufA, (float*)d_out, nu * D, Nf);

    // 5. propagation layers: wave-per-node gather, acc fused
    __hip_bfloat16* A  = bufA;
    __hip_bfloat16* Bp = bufB;
    const int waves_per_block = B256 / 64;
    const int ggrid = blocks(N, waves_per_block);
    for (int l = 0; l < NUM_LAYERS; ++l) {
        int write_B = (l < NUM_LAYERS - 1) ? 1 : 0;
        gather_kernel<<<ggrid, B256, 0, stream>>>(row_start, csr, A, Bp, (float*)d_out, N, write_B);
        __hip_bfloat16* t = A; A = Bp; Bp = t;
    }

    // 6. final scale by 1/25
    scale_kernel<<<blocks(Nf / 4, B256), B256, 0, stream>>>((float*)d_out, Nf / 4, 1.0f / 25.0f);
}